// Round 1
// baseline (368.234 us; speedup 1.0000x reference)
//
#include <hip/hip_runtime.h>
#include <math.h>

#define H 256
#define N2 32
#define Bsz 8
#define Lseq 4096
#define BH (Bsz*H)          // 2048 sequences
#define NCH 32              // chunks along L
#define LC (Lseq/NCH)       // 128 chunk length
#define HN (H*N2)           // 8192

// workspace layout (floats):
//  P : 6*HN              [wr, wi, wLr, wLi, 2*Ctr, 2*Cti]
//  S : BH*NCH*N2*2       chunk states (pass1: local finals; pass2 rewrites to incoming)
//  y : BH*Lseq           post-GELU activations
#define P_OFF 0
#define S_OFF (6*HN)
#define Y_OFF (S_OFF + BH*NCH*N2*2)

// ---------------- K0: per-(h,n) parameters ----------------
__global__ void k_params(const float* __restrict__ log_dt, const float* __restrict__ C,
                         const float* __restrict__ lar, const float* __restrict__ aim,
                         float* __restrict__ P) {
  int i = blockIdx.x * blockDim.x + threadIdx.x;
  if (i >= HN) return;
  int h = i >> 5;
  float dt  = expf(log_dt[h]);
  float Ar  = -expf(lar[i]);
  float Ai  = aim[i];
  float dAr = Ar * dt, dAi = Ai * dt;
  float er  = expf(dAr);
  float wr  = er * cosf(dAi);
  float wi  = er * sinf(dAi);
  float eLr = expf(dAr * (float)LC);
  float wLr = eLr * cosf(dAi * (float)LC);
  float wLi = eLr * sinf(dAi * (float)LC);
  // Ct = C * (w - 1) / A   (complex)
  float emr = wr - 1.0f, emi = wi;
  float inv = 1.0f / (Ar * Ar + Ai * Ai);
  float qr  = (emr * Ar + emi * Ai) * inv;
  float qi  = (emi * Ar - emr * Ai) * inv;
  float Cr  = C[2 * i], Ci = C[2 * i + 1];
  float ctr = Cr * qr - Ci * qi;
  float cti = Cr * qi + Ci * qr;
  P[i]          = wr;
  P[HN + i]     = wi;
  P[2 * HN + i] = wLr;
  P[3 * HN + i] = wLi;
  P[4 * HN + i] = 2.0f * ctr;   // fold the 2*Re(...) factor in here
  P[5 * HN + i] = 2.0f * cti;
}

// ---------------- K1: pass 1, chunk-local scans -> S_c ----------------
__global__ __launch_bounds__(256) void k_scan1(const float* __restrict__ u,
                                               const float* __restrict__ P,
                                               float* __restrict__ S) {
  int t  = blockIdx.x * 256 + threadIdx.x;  // t < BH*NCH*N2
  int n  = t & 31;
  int c  = (t >> 5) & (NCH - 1);
  int bh = t >> 10;
  int h  = bh & (H - 1);
  int hn = (h << 5) + n;
  float wr = P[hn], wi = P[HN + hn];
  const float* up = u + bh * Lseq + c * LC;
  float xr = 0.f, xi = 0.f;
#pragma unroll 4
  for (int j = 0; j < LC; j++) {
    float uv = up[j];
    float nr = fmaf(wr, xr, fmaf(-wi, xi, uv));
    float ni = fmaf(wr, xi, wi * xr);
    xr = nr; xi = ni;
  }
  int si = (((bh * NCH + c) << 5) + n) << 1;
  S[si] = xr; S[si + 1] = xi;
}

// ---------------- K2: pass 2, serial prefix over chunks (in place) ----------------
__global__ void k_prefix(const float* __restrict__ P, float* __restrict__ S) {
  int t = blockIdx.x * blockDim.x + threadIdx.x;  // t < BH*N2
  if (t >= BH * N2) return;
  int n = t & 31, bh = t >> 5;
  int hn = ((bh & (H - 1)) << 5) + n;
  float wLr = P[2 * HN + hn], wLi = P[3 * HN + hn];
  float fr = 0.f, fi = 0.f;                 // F_{-1} = 0
  for (int c = 0; c < NCH; c++) {
    int si = (((bh * NCH + c) << 5) + n) << 1;
    float sr = S[si], s1 = S[si + 1];
    S[si] = fr; S[si + 1] = fi;             // incoming state for chunk c = F_{c-1}
    float nr = fmaf(wLr, fr, fmaf(-wLi, fi, sr));
    float ni = fmaf(wLr, fi, fmaf(wLi, fr, s1));
    fr = nr; fi = ni;
  }
}

// ---------------- K3: pass 3, full scan + reduce_n + D*u + exact GELU -> y ----------------
__global__ __launch_bounds__(256) void k_scan2(const float* __restrict__ u,
                                               const float* __restrict__ P,
                                               const float* __restrict__ S,
                                               const float* __restrict__ Dp,
                                               float* __restrict__ y) {
  int t  = blockIdx.x * 256 + threadIdx.x;  // t < BH*NCH*4
  int ng = t & 3;                           // 4 lanes/group, 8 n each
  int g  = t >> 2;
  int c  = g & (NCH - 1);
  int bh = g >> 5;
  int h  = bh & (H - 1);
  int n0 = ng << 3;
  float wr[8], wi[8], cr[8], ci[8], xr[8], xi[8];
#pragma unroll
  for (int q = 0; q < 8; q++) {
    int hn = (h << 5) + n0 + q;
    wr[q] = P[hn];          wi[q] = P[HN + hn];
    cr[q] = P[4 * HN + hn]; ci[q] = P[5 * HN + hn];
    int si = (((bh * NCH + c) << 5) + n0 + q) << 1;
    xr[q] = S[si]; xi[q] = S[si + 1];       // incoming full-history state
  }
  float Dh = Dp[h];
  const float* up = u + bh * Lseq + c * LC;
  float*       yp = y + bh * Lseq + c * LC;
  for (int j = 0; j < LC; j++) {
    float uv = up[j];
    float part = 0.f;
#pragma unroll
    for (int q = 0; q < 8; q++) {
      float nr = fmaf(wr[q], xr[q], fmaf(-wi[q], xi[q], uv));
      float ni = fmaf(wr[q], xi[q], wi[q] * xr[q]);
      xr[q] = nr; xi[q] = ni;
      part = fmaf(cr[q], nr, part);
      part = fmaf(-ci[q], ni, part);
    }
    part += __shfl_xor(part, 1);
    part += __shfl_xor(part, 2);
    if (ng == 0) {
      float v  = fmaf(Dh, uv, part);
      float ge = 0.5f * v * (1.0f + erff(v * 0.70710678118654752f));  // exact GELU
      yp[j] = ge;
    }
  }
}

// ---------------- K4: z = W@y + b ; out = a * sigmoid(g) ----------------
#define KT 16
__global__ __launch_bounds__(256) void k_gemm(const float* __restrict__ y,
                                              const float* __restrict__ W,
                                              const float* __restrict__ bias,
                                              float* __restrict__ out) {
  __shared__ float Wl[KT][516];   // [k][o], +4 pad: aligned float4 rows, conflict-light
  __shared__ float yl[KT][32];    // [k][l]
  int b   = blockIdx.y;
  int l0  = blockIdx.x * 32;
  int tid = threadIdx.x;
  int lg  = tid & 7;              // 8 l-groups x 4 l
  int og  = tid >> 3;             // 32 o-groups x 8 o
  float acc_a[8][4] = {{0.f}};
  float acc_g[8][4] = {{0.f}};
  for (int kt = 0; kt < H; kt += KT) {
    // stage W tile: 512 rows x KT cols, transposed into Wl[k][o]
    for (int e = tid; e < 512 * (KT / 4); e += 256) {  // 2048 float4s
      int row = e >> 2, seg = e & 3;
      float4 v = *(const float4*)&W[row * H + kt + seg * 4];
      Wl[seg * 4 + 0][row] = v.x;
      Wl[seg * 4 + 1][row] = v.y;
      Wl[seg * 4 + 2][row] = v.z;
      Wl[seg * 4 + 3][row] = v.w;
    }
    // stage y tile: KT k-rows x 32 l
    if (tid < KT * 8) {
      int kk = tid >> 3, s = tid & 7;
      float4 v = *(const float4*)&y[(b * H + kt + kk) * Lseq + l0 + s * 4];
      *(float4*)&yl[kk][s * 4] = v;
    }
    __syncthreads();
#pragma unroll
    for (int k = 0; k < KT; k++) {
      float4 yv = *(const float4*)&yl[k][lg * 4];
      const float4* wra = (const float4*)&Wl[k][og * 8];
      const float4* wrg = (const float4*)&Wl[k][256 + og * 8];
      float4 wa0 = wra[0], wa1 = wra[1];
      float4 wg0 = wrg[0], wg1 = wrg[1];
      float wa[8] = {wa0.x, wa0.y, wa0.z, wa0.w, wa1.x, wa1.y, wa1.z, wa1.w};
      float wg[8] = {wg0.x, wg0.y, wg0.z, wg0.w, wg1.x, wg1.y, wg1.z, wg1.w};
      float yj[4] = {yv.x, yv.y, yv.z, yv.w};
#pragma unroll
      for (int i = 0; i < 8; i++) {
#pragma unroll
        for (int j = 0; j < 4; j++) {
          acc_a[i][j] = fmaf(wa[i], yj[j], acc_a[i][j]);
          acc_g[i][j] = fmaf(wg[i], yj[j], acc_g[i][j]);
        }
      }
    }
    __syncthreads();
  }
  // epilogue: bias + GLU, coalesced float4 stores (lg fast across lanes)
#pragma unroll
  for (int i = 0; i < 8; i++) {
    int o = og * 8 + i;
    float ba = bias[o], bg = bias[H + o];
    float4 r;
    float vals[4];
#pragma unroll
    for (int j = 0; j < 4; j++) {
      float a = acc_a[i][j] + ba;
      float gg = acc_g[i][j] + bg;
      vals[j] = a / (1.0f + expf(-gg));
    }
    r.x = vals[0]; r.y = vals[1]; r.z = vals[2]; r.w = vals[3];
    *(float4*)&out[(b * H + o) * Lseq + l0 + lg * 4] = r;
  }
}

extern "C" void kernel_launch(void* const* d_in, const int* in_sizes, int n_in,
                              void* d_out, int out_size, void* d_ws, size_t ws_size,
                              hipStream_t stream) {
  const float* u      = (const float*)d_in[0];
  const float* log_dt = (const float*)d_in[1];
  const float* C      = (const float*)d_in[2];
  const float* lar    = (const float*)d_in[3];
  const float* aim    = (const float*)d_in[4];
  const float* Dp     = (const float*)d_in[5];
  const float* W      = (const float*)d_in[6];
  const float* bias   = (const float*)d_in[7];
  float* out = (float*)d_out;
  float* ws  = (float*)d_ws;
  float* P = ws + P_OFF;
  float* S = ws + S_OFF;
  float* yv = ws + Y_OFF;

  hipLaunchKernelGGL(k_params, dim3(HN / 256), dim3(256), 0, stream, log_dt, C, lar, aim, P);
  hipLaunchKernelGGL(k_scan1,  dim3(BH * NCH * N2 / 256), dim3(256), 0, stream, u, P, S);
  hipLaunchKernelGGL(k_prefix, dim3(BH * N2 / 256), dim3(256), 0, stream, P, S);
  hipLaunchKernelGGL(k_scan2,  dim3(BH * NCH * 4 / 256), dim3(256), 0, stream, u, P, S, Dp, yv);
  hipLaunchKernelGGL(k_gemm,   dim3(Lseq / 32, Bsz), dim3(256), 0, stream, yv, W, bias, out);
}

// Round 2
// 273.067 us; speedup vs baseline: 1.3485x; 1.3485x over previous
//
#include <hip/hip_runtime.h>
#include <math.h>

#define H 256
#define N2 32
#define Bsz 8
#define Lseq 4096
#define BH (Bsz*H)          // 2048 sequences
#define NCH 32              // chunks along L
#define LC (Lseq/NCH)       // 128 chunk length
#define HN (H*N2)           // 8192

// workspace layout (floats):
//  P : 6*HN              [wr, wi, wLr, wLi, 2*Ctr, 2*Cti]
//  S : BH*NCH*N2*2       chunk states (pass1: local finals; pass2 rewrites to incoming)
//  y : BH*Lseq           post-GELU activations (fp32)
#define P_OFF 0
#define S_OFF (6*HN)
#define Y_OFF (S_OFF + BH*NCH*N2*2)

typedef __attribute__((ext_vector_type(8))) short bf16x8;
typedef __attribute__((ext_vector_type(4))) float f32x4;

__device__ __forceinline__ unsigned short f2bf(float x) {
  union { float f; unsigned int u; } v; v.f = x;
  unsigned int r = v.u + 0x7fffu + ((v.u >> 16) & 1u);  // round-to-nearest-even
  return (unsigned short)(r >> 16);
}
__device__ __forceinline__ unsigned int packbf(float lo, float hi) {
  return (unsigned int)f2bf(lo) | ((unsigned int)f2bf(hi) << 16);
}

// ---------------- K0: per-(h,n) parameters ----------------
__global__ void k_params(const float* __restrict__ log_dt, const float* __restrict__ C,
                         const float* __restrict__ lar, const float* __restrict__ aim,
                         float* __restrict__ P) {
  int i = blockIdx.x * blockDim.x + threadIdx.x;
  if (i >= HN) return;
  int h = i >> 5;
  float dt  = expf(log_dt[h]);
  float Ar  = -expf(lar[i]);
  float Ai  = aim[i];
  float dAr = Ar * dt, dAi = Ai * dt;
  float er  = expf(dAr);
  float wr  = er * cosf(dAi);
  float wi  = er * sinf(dAi);
  float eLr = expf(dAr * (float)LC);
  float wLr = eLr * cosf(dAi * (float)LC);
  float wLi = eLr * sinf(dAi * (float)LC);
  // Ct = C * (w - 1) / A   (complex)
  float emr = wr - 1.0f, emi = wi;
  float inv = 1.0f / (Ar * Ar + Ai * Ai);
  float qr  = (emr * Ar + emi * Ai) * inv;
  float qi  = (emi * Ar - emr * Ai) * inv;
  float Cr  = C[2 * i], Ci = C[2 * i + 1];
  float ctr = Cr * qr - Ci * qi;
  float cti = Cr * qi + Ci * qr;
  P[i]          = wr;
  P[HN + i]     = wi;
  P[2 * HN + i] = wLr;
  P[3 * HN + i] = wLi;
  P[4 * HN + i] = 2.0f * ctr;   // fold the 2*Re(...) factor in here
  P[5 * HN + i] = 2.0f * cti;
}

// ---------------- K1: pass 1, chunk-local scans -> S_c ----------------
__global__ __launch_bounds__(256) void k_scan1(const float* __restrict__ u,
                                               const float* __restrict__ P,
                                               float* __restrict__ S) {
  int t  = blockIdx.x * 256 + threadIdx.x;  // t < BH*NCH*N2
  int n  = t & 31;
  int c  = (t >> 5) & (NCH - 1);
  int bh = t >> 10;
  int h  = bh & (H - 1);
  int hn = (h << 5) + n;
  float wr = P[hn], wi = P[HN + hn];
  const float* up = u + bh * Lseq + c * LC;
  float xr = 0.f, xi = 0.f;
#pragma unroll 4
  for (int j = 0; j < LC; j++) {
    float uv = up[j];
    float nr = fmaf(wr, xr, fmaf(-wi, xi, uv));
    float ni = fmaf(wr, xi, wi * xr);
    xr = nr; xi = ni;
  }
  int si = (((bh * NCH + c) << 5) + n) << 1;
  S[si] = xr; S[si + 1] = xi;
}

// ---------------- K2: pass 2, serial prefix over chunks (in place) ----------------
__global__ void k_prefix(const float* __restrict__ P, float* __restrict__ S) {
  int t = blockIdx.x * blockDim.x + threadIdx.x;  // t < BH*N2
  if (t >= BH * N2) return;
  int n = t & 31, bh = t >> 5;
  int hn = ((bh & (H - 1)) << 5) + n;
  float wLr = P[2 * HN + hn], wLi = P[3 * HN + hn];
  float fr = 0.f, fi = 0.f;                 // F_{-1} = 0
  for (int c = 0; c < NCH; c++) {
    int si = (((bh * NCH + c) << 5) + n) << 1;
    float sr = S[si], s1 = S[si + 1];
    S[si] = fr; S[si + 1] = fi;             // incoming state for chunk c = F_{c-1}
    float nr = fmaf(wLr, fr, fmaf(-wLi, fi, sr));
    float ni = fmaf(wLr, fi, fmaf(wLi, fr, s1));
    fr = nr; fi = ni;
  }
}

// ---------------- K3: pass 3, full scan + reduce_n + D*u + exact GELU -> y ----------------
__global__ __launch_bounds__(256) void k_scan2(const float* __restrict__ u,
                                               const float* __restrict__ P,
                                               const float* __restrict__ S,
                                               const float* __restrict__ Dp,
                                               float* __restrict__ y) {
  int t  = blockIdx.x * 256 + threadIdx.x;  // t < BH*NCH*4
  int ng = t & 3;                           // 4 lanes/group, 8 n each
  int g  = t >> 2;
  int c  = g & (NCH - 1);
  int bh = g >> 5;
  int h  = bh & (H - 1);
  int n0 = ng << 3;
  float wr[8], wi[8], cr[8], ci[8], xr[8], xi[8];
#pragma unroll
  for (int q = 0; q < 8; q++) {
    int hn = (h << 5) + n0 + q;
    wr[q] = P[hn];          wi[q] = P[HN + hn];
    cr[q] = P[4 * HN + hn]; ci[q] = P[5 * HN + hn];
    int si = (((bh * NCH + c) << 5) + n0 + q) << 1;
    xr[q] = S[si]; xi[q] = S[si + 1];       // incoming full-history state
  }
  float Dh = Dp[h];
  const float* up = u + bh * Lseq + c * LC;
  float*       yp = y + bh * Lseq + c * LC;
  for (int j = 0; j < LC; j++) {
    float uv = up[j];
    float part = 0.f;
#pragma unroll
    for (int q = 0; q < 8; q++) {
      float nr = fmaf(wr[q], xr[q], fmaf(-wi[q], xi[q], uv));
      float ni = fmaf(wr[q], xi[q], wi[q] * xr[q]);
      xr[q] = nr; xi[q] = ni;
      part = fmaf(cr[q], nr, part);
      part = fmaf(-ci[q], ni, part);
    }
    part += __shfl_xor(part, 1);
    part += __shfl_xor(part, 2);
    if (ng == 0) {
      float v  = fmaf(Dh, uv, part);
      float ge = 0.5f * v * (1.0f + erff(v * 0.70710678118654752f));  // exact GELU
      yp[j] = ge;
    }
  }
}

// ---------------- K4: MFMA bf16 GEMM: z = W@y + b ; out = a * sigmoid(g) ----------------
// Block tile: 64 o-pairs (a-rows o0..o0+63, g-rows 256+o0..) x 128 l, K-chunks of 64.
// LDS layouts: Ws[r][k] r: 0..63 = a-rows, 64..127 = g-rows; Ys[l][k] (transposed from y).
// Fragments per mfma_f32_16x16x32_bf16: A[m=lane&15][k=quad*8+j], B[k=quad*8+j][n=lane&15],
// D: col=lane&15 (l), row=quad*4+reg (o). All frag loads are aligned ds_read_b128.
__global__ __launch_bounds__(256) void k_gemm(const float* __restrict__ y,
                                              const float* __restrict__ W,
                                              const float* __restrict__ bias,
                                              float* __restrict__ out) {
  __shared__ unsigned short Ws[128][72];   // stride 72 bf16 = 144 B (16B-aligned rows)
  __shared__ unsigned short Ys[128][72];
  int tid  = threadIdx.x;
  int l0   = blockIdx.x * 128;
  int o0   = blockIdx.y * 64;
  int bb   = blockIdx.z;
  int wave = tid >> 6;
  int lane = tid & 63;
  int wo   = wave & 1;        // o-half of block tile (32 o-pairs)
  int wl   = wave >> 1;       // l-half (64 l)
  int n    = lane & 15;
  int quad = lane >> 4;

  f32x4 acc_a[2][4] = {};     // [mt][lt]
  f32x4 acc_g[2][4] = {};

  for (int kk = 0; kk < H; kk += 64) {
    // ---- stage W tile (fp32 -> bf16): 128 rows x 64 k ----
#pragma unroll
    for (int i = 0; i < 8; i++) {
      int e  = tid + i * 256;            // 0..2047 float4s
      int r  = e >> 4, c4 = e & 15;
      int gr = (r < 64) ? (o0 + r) : (192 + o0 + r);   // g-rows: 256 + o0 + (r-64)
      float4 v = *(const float4*)&W[gr * H + kk + c4 * 4];
      *(unsigned int*)&Ws[r][c4 * 4]     = packbf(v.x, v.y);
      *(unsigned int*)&Ws[r][c4 * 4 + 2] = packbf(v.z, v.w);
    }
    // ---- stage y tile transposed (fp32 -> bf16): Ys[l][k], paired k rows for b32 writes ----
#pragma unroll
    for (int i = 0; i < 4; i++) {
      int e  = tid + i * 256;            // 0..1023 double-row float4s
      int k2 = e >> 5, c4 = e & 31;      // k2: 0..31 (k = 2*k2, 2*k2+1)
      const float* base = &y[(bb * H + kk + 2 * k2) * Lseq + l0 + c4 * 4];
      float4 va = *(const float4*)base;
      float4 vb = *(const float4*)(base + Lseq);
      int col = 2 * k2;
      *(unsigned int*)&Ys[c4 * 4 + 0][col] = packbf(va.x, vb.x);
      *(unsigned int*)&Ys[c4 * 4 + 1][col] = packbf(va.y, vb.y);
      *(unsigned int*)&Ys[c4 * 4 + 2][col] = packbf(va.z, vb.z);
      *(unsigned int*)&Ys[c4 * 4 + 3][col] = packbf(va.w, vb.w);
    }
    __syncthreads();
    // ---- MFMA inner loop over this K-chunk ----
#pragma unroll
    for (int ks = 0; ks < 64; ks += 32) {
      int kc = ks + quad * 8;
      bf16x8 af_a[2], af_g[2], bfr[4];
#pragma unroll
      for (int mt = 0; mt < 2; mt++) {
        af_a[mt] = *(const bf16x8*)&Ws[wo * 32 + mt * 16 + n][kc];
        af_g[mt] = *(const bf16x8*)&Ws[64 + wo * 32 + mt * 16 + n][kc];
      }
#pragma unroll
      for (int lt = 0; lt < 4; lt++)
        bfr[lt] = *(const bf16x8*)&Ys[wl * 64 + lt * 16 + n][kc];
#pragma unroll
      for (int mt = 0; mt < 2; mt++)
#pragma unroll
        for (int lt = 0; lt < 4; lt++) {
          acc_a[mt][lt] = __builtin_amdgcn_mfma_f32_16x16x32_bf16(af_a[mt], bfr[lt], acc_a[mt][lt], 0, 0, 0);
          acc_g[mt][lt] = __builtin_amdgcn_mfma_f32_16x16x32_bf16(af_g[mt], bfr[lt], acc_g[mt][lt], 0, 0, 0);
        }
    }
    __syncthreads();
  }
  // ---- epilogue: bias + GLU ----
#pragma unroll
  for (int mt = 0; mt < 2; mt++) {
    int ob = o0 + wo * 32 + mt * 16 + quad * 4;
#pragma unroll
    for (int reg = 0; reg < 4; reg++) {
      int op = ob + reg;
      float ba = bias[op], bg = bias[H + op];
      float* orow = &out[(bb * H + op) * Lseq + l0 + wl * 64 + n];
#pragma unroll
      for (int lt = 0; lt < 4; lt++) {
        float a = acc_a[mt][lt][reg] + ba;
        float g = acc_g[mt][lt][reg] + bg;
        orow[lt * 16] = a / (1.0f + expf(-g));
      }
    }
  }
}

extern "C" void kernel_launch(void* const* d_in, const int* in_sizes, int n_in,
                              void* d_out, int out_size, void* d_ws, size_t ws_size,
                              hipStream_t stream) {
  const float* u      = (const float*)d_in[0];
  const float* log_dt = (const float*)d_in[1];
  const float* C      = (const float*)d_in[2];
  const float* lar    = (const float*)d_in[3];
  const float* aim    = (const float*)d_in[4];
  const float* Dp     = (const float*)d_in[5];
  const float* W      = (const float*)d_in[6];
  const float* bias   = (const float*)d_in[7];
  float* out = (float*)d_out;
  float* ws  = (float*)d_ws;
  float* P  = ws + P_OFF;
  float* S  = ws + S_OFF;
  float* yv = ws + Y_OFF;

  hipLaunchKernelGGL(k_params, dim3(HN / 256), dim3(256), 0, stream, log_dt, C, lar, aim, P);
  hipLaunchKernelGGL(k_scan1,  dim3(BH * NCH * N2 / 256), dim3(256), 0, stream, u, P, S);
  hipLaunchKernelGGL(k_prefix, dim3(BH * N2 / 256), dim3(256), 0, stream, P, S);
  hipLaunchKernelGGL(k_scan2,  dim3(BH * NCH * 4 / 256), dim3(256), 0, stream, u, P, S, Dp, yv);
  hipLaunchKernelGGL(k_gemm,   dim3(Lseq / 128, H / 64, Bsz), dim3(256), 0, stream, yv, W, bias, out);
}

// Round 3
// 212.463 us; speedup vs baseline: 1.7332x; 1.2852x over previous
//
#include <hip/hip_runtime.h>
#include <math.h>

#define H 256
#define N2 32
#define Bsz 8
#define Lseq 4096
#define BH (Bsz*H)          // 2048 sequences
#define NCH 32              // chunks along L
#define LC (Lseq/NCH)       // 128 chunk length
#define HN (H*N2)           // 8192

// workspace layout (floats):
//  P : 6*HN              [wr, wi, wLr, wLi, 2*Ctr, 2*Cti]
//  S : BH*NCH*N2*2       chunk states (pass1: local finals; pass2 rewrites to incoming)
//  y : BH*Lseq           post-GELU activations (fp32)
#define P_OFF 0
#define S_OFF (6*HN)
#define Y_OFF (S_OFF + BH*NCH*N2*2)

typedef __attribute__((ext_vector_type(8))) short bf16x8;
typedef __attribute__((ext_vector_type(4))) float f32x4;

__device__ __forceinline__ unsigned short f2bf(float x) {
  union { float f; unsigned int u; } v; v.f = x;
  unsigned int r = v.u + 0x7fffu + ((v.u >> 16) & 1u);  // round-to-nearest-even
  return (unsigned short)(r >> 16);
}
__device__ __forceinline__ unsigned int packbf(float lo, float hi) {
  return (unsigned int)f2bf(lo) | ((unsigned int)f2bf(hi) << 16);
}

// ---------------- K0: per-(h,n) parameters ----------------
__global__ void k_params(const float* __restrict__ log_dt, const float* __restrict__ C,
                         const float* __restrict__ lar, const float* __restrict__ aim,
                         float* __restrict__ P) {
  int i = blockIdx.x * blockDim.x + threadIdx.x;
  if (i >= HN) return;
  int h = i >> 5;
  float dt  = expf(log_dt[h]);
  float Ar  = -expf(lar[i]);
  float Ai  = aim[i];
  float dAr = Ar * dt, dAi = Ai * dt;
  float er  = expf(dAr);
  float wr  = er * cosf(dAi);
  float wi  = er * sinf(dAi);
  float eLr = expf(dAr * (float)LC);
  float wLr = eLr * cosf(dAi * (float)LC);
  float wLi = eLr * sinf(dAi * (float)LC);
  // Ct = C * (w - 1) / A   (complex)
  float emr = wr - 1.0f, emi = wi;
  float inv = 1.0f / (Ar * Ar + Ai * Ai);
  float qr  = (emr * Ar + emi * Ai) * inv;
  float qi  = (emi * Ar - emr * Ai) * inv;
  float Cr  = C[2 * i], Ci = C[2 * i + 1];
  float ctr = Cr * qr - Ci * qi;
  float cti = Cr * qi + Ci * qr;
  P[i]          = wr;
  P[HN + i]     = wi;
  P[2 * HN + i] = wLr;
  P[3 * HN + i] = wLi;
  P[4 * HN + i] = 2.0f * ctr;   // fold the 2*Re(...) factor in here
  P[5 * HN + i] = 2.0f * cti;
}

// ---------------- K1: pass 1, chunk-local scans -> S_c ----------------
__global__ __launch_bounds__(256) void k_scan1(const float* __restrict__ u,
                                               const float* __restrict__ P,
                                               float* __restrict__ S) {
  int t  = blockIdx.x * 256 + threadIdx.x;  // t < BH*NCH*N2
  int n  = t & 31;
  int c  = (t >> 5) & (NCH - 1);
  int bh = t >> 10;
  int h  = bh & (H - 1);
  int hn = (h << 5) + n;
  float wr = P[hn], wi = P[HN + hn];
  const float* up = u + bh * Lseq + c * LC;
  float xr = 0.f, xi = 0.f;
  for (int j = 0; j < LC; j += 4) {
    float4 uv = *(const float4*)(up + j);
#pragma unroll
    for (int jj = 0; jj < 4; jj++) {
      float u1 = ((const float*)&uv)[jj];
      float nr = fmaf(wr, xr, fmaf(-wi, xi, u1));
      float ni = fmaf(wr, xi, wi * xr);
      xr = nr; xi = ni;
    }
  }
  int si = (((bh * NCH + c) << 5) + n) << 1;
  S[si] = xr; S[si + 1] = xi;
}

// ---------------- K2: pass 2, serial prefix over chunks (in place) ----------------
__global__ void k_prefix(const float* __restrict__ P, float* __restrict__ S) {
  int t = blockIdx.x * blockDim.x + threadIdx.x;  // t < BH*N2
  if (t >= BH * N2) return;
  int n = t & 31, bh = t >> 5;
  int hn = ((bh & (H - 1)) << 5) + n;
  float wLr = P[2 * HN + hn], wLi = P[3 * HN + hn];
  float fr = 0.f, fi = 0.f;                 // F_{-1} = 0
  for (int c = 0; c < NCH; c++) {
    int si = (((bh * NCH + c) << 5) + n) << 1;
    float sr = S[si], s1 = S[si + 1];
    S[si] = fr; S[si + 1] = fi;             // incoming state for chunk c = F_{c-1}
    float nr = fmaf(wLr, fr, fmaf(-wLi, fi, sr));
    float ni = fmaf(wLr, fi, fmaf(wLi, fr, s1));
    fr = nr; fi = ni;
  }
}

// ---------------- K3: pass 3, full scan + reduce_n + D*u + exact GELU -> y ----------------
// Block: 256 threads = 64 groups x 4 lanes; 64 consecutive (bh,c) chunks = one
// contiguous 8192-float span of y. Scan results staged in padded LDS, then a
// block-wide float4 copy-out gives fully-coalesced HBM writes.
// GELU is distributed: after the 2-butterfly reduce all 4 lanes hold the 4 sums
// of a j-quad; lane ng evaluates erf for j+ng (no divergence, erf cost / 4).
__global__ __launch_bounds__(256) void k_scan2(const float* __restrict__ u,
                                               const float* __restrict__ P,
                                               const float* __restrict__ S,
                                               const float* __restrict__ Dp,
                                               float* __restrict__ y) {
  __shared__ float ybuf[64][132];           // pad +4: write banks (4*gl+j+ng)%32 fully spread
  int tid = threadIdx.x;
  int ng  = tid & 3;                        // 4 lanes/group, 8 n each
  int gl  = tid >> 2;                       // local group 0..63
  int g   = blockIdx.x * 64 + gl;           // global group = bh*NCH + c
  int c   = g & (NCH - 1);
  int bh  = g >> 5;
  int h   = bh & (H - 1);
  int n0  = ng << 3;
  float wr[8], wi[8], cr[8], ci[8], xr[8], xi[8];
#pragma unroll
  for (int q = 0; q < 8; q++) {
    int hn = (h << 5) + n0 + q;
    wr[q] = P[hn];          wi[q] = P[HN + hn];
    cr[q] = P[4 * HN + hn]; ci[q] = P[5 * HN + hn];
    int si = (((bh * NCH + c) << 5) + n0 + q) << 1;
    xr[q] = S[si]; xi[q] = S[si + 1];       // incoming full-history state
  }
  float Dh = Dp[h];
  const float* up = u + g * LC;
  for (int j = 0; j < LC; j += 4) {
    float4 uv4 = *(const float4*)(up + j);
    float s[4];
#pragma unroll
    for (int jj = 0; jj < 4; jj++) {
      float uv = ((const float*)&uv4)[jj];
      float part = 0.f;
#pragma unroll
      for (int q = 0; q < 8; q++) {
        float nr = fmaf(wr[q], xr[q], fmaf(-wi[q], xi[q], uv));
        float ni = fmaf(wr[q], xi[q], wi[q] * xr[q]);
        xr[q] = nr; xi[q] = ni;
        part = fmaf(cr[q], nr, part);
        part = fmaf(-ci[q], ni, part);
      }
      part += __shfl_xor(part, 1);
      part += __shfl_xor(part, 2);          // now all 4 lanes hold the full n-sum
      s[jj] = fmaf(Dh, uv, part);
    }
    float v  = (ng == 0) ? s[0] : (ng == 1) ? s[1] : (ng == 2) ? s[2] : s[3];
    float ge = 0.5f * v * (1.0f + erff(v * 0.70710678118654752f));  // exact GELU
    ybuf[gl][j + ng] = ge;
  }
  __syncthreads();
  // coalesced copy-out: this block's span is y[blockIdx.x*8192 .. +8192)
  float* yo = y + blockIdx.x * (64 * LC);
#pragma unroll
  for (int i = 0; i < 8; i++) {
    int e   = tid + i * 256;                // float4 index 0..2047
    int row = e >> 5, col4 = e & 31;
    *(float4*)(yo + e * 4) = *(const float4*)&ybuf[row][col4 * 4];
  }
}

// ---------------- K4: MFMA bf16 GEMM: z = W@y + b ; out = a * sigmoid(g) ----------------
// Block tile: 64 o-pairs (a-rows o0..o0+63, g-rows 256+o0..) x 128 l, K-chunks of 64.
// LDS layouts: Ws[r][k] r: 0..63 = a-rows, 64..127 = g-rows; Ys[l][k] (transposed from y).
// Fragments per mfma_f32_16x16x32_bf16: A[m=lane&15][k=quad*8+j], B[k=quad*8+j][n=lane&15],
// D: col=lane&15 (l), row=quad*4+reg (o). All frag loads are aligned ds_read_b128.
__global__ __launch_bounds__(256) void k_gemm(const float* __restrict__ y,
                                              const float* __restrict__ W,
                                              const float* __restrict__ bias,
                                              float* __restrict__ out) {
  __shared__ unsigned short Ws[128][72];   // stride 72 bf16 = 144 B (16B-aligned rows)
  __shared__ unsigned short Ys[128][72];
  int tid  = threadIdx.x;
  int l0   = blockIdx.x * 128;
  int o0   = blockIdx.y * 64;
  int bb   = blockIdx.z;
  int wave = tid >> 6;
  int lane = tid & 63;
  int wo   = wave & 1;        // o-half of block tile (32 o-pairs)
  int wl   = wave >> 1;       // l-half (64 l)
  int n    = lane & 15;
  int quad = lane >> 4;

  f32x4 acc_a[2][4] = {};     // [mt][lt]
  f32x4 acc_g[2][4] = {};

  for (int kk = 0; kk < H; kk += 64) {
    // ---- stage W tile (fp32 -> bf16): 128 rows x 64 k ----
#pragma unroll
    for (int i = 0; i < 8; i++) {
      int e  = tid + i * 256;            // 0..2047 float4s
      int r  = e >> 4, c4 = e & 15;
      int gr = (r < 64) ? (o0 + r) : (192 + o0 + r);   // g-rows: 256 + o0 + (r-64)
      float4 v = *(const float4*)&W[gr * H + kk + c4 * 4];
      *(unsigned int*)&Ws[r][c4 * 4]     = packbf(v.x, v.y);
      *(unsigned int*)&Ws[r][c4 * 4 + 2] = packbf(v.z, v.w);
    }
    // ---- stage y tile transposed (fp32 -> bf16): Ys[l][k], paired k rows for b32 writes ----
#pragma unroll
    for (int i = 0; i < 4; i++) {
      int e  = tid + i * 256;            // 0..1023 double-row float4s
      int k2 = e >> 5, c4 = e & 31;      // k2: 0..31 (k = 2*k2, 2*k2+1)
      const float* base = &y[(bb * H + kk + 2 * k2) * Lseq + l0 + c4 * 4];
      float4 va = *(const float4*)base;
      float4 vb = *(const float4*)(base + Lseq);
      int col = 2 * k2;
      *(unsigned int*)&Ys[c4 * 4 + 0][col] = packbf(va.x, vb.x);
      *(unsigned int*)&Ys[c4 * 4 + 1][col] = packbf(va.y, vb.y);
      *(unsigned int*)&Ys[c4 * 4 + 2][col] = packbf(va.z, vb.z);
      *(unsigned int*)&Ys[c4 * 4 + 3][col] = packbf(va.w, vb.w);
    }
    __syncthreads();
    // ---- MFMA inner loop over this K-chunk ----
#pragma unroll
    for (int ks = 0; ks < 64; ks += 32) {
      int kc = ks + quad * 8;
      bf16x8 af_a[2], af_g[2], bfr[4];
#pragma unroll
      for (int mt = 0; mt < 2; mt++) {
        af_a[mt] = *(const bf16x8*)&Ws[wo * 32 + mt * 16 + n][kc];
        af_g[mt] = *(const bf16x8*)&Ws[64 + wo * 32 + mt * 16 + n][kc];
      }
#pragma unroll
      for (int lt = 0; lt < 4; lt++)
        bfr[lt] = *(const bf16x8*)&Ys[wl * 64 + lt * 16 + n][kc];
#pragma unroll
      for (int mt = 0; mt < 2; mt++)
#pragma unroll
        for (int lt = 0; lt < 4; lt++) {
          acc_a[mt][lt] = __builtin_amdgcn_mfma_f32_16x16x32_bf16(af_a[mt], bfr[lt], acc_a[mt][lt], 0, 0, 0);
          acc_g[mt][lt] = __builtin_amdgcn_mfma_f32_16x16x32_bf16(af_g[mt], bfr[lt], acc_g[mt][lt], 0, 0, 0);
        }
    }
    __syncthreads();
  }
  // ---- epilogue: bias + GLU ----
#pragma unroll
  for (int mt = 0; mt < 2; mt++) {
    int ob = o0 + wo * 32 + mt * 16 + quad * 4;
#pragma unroll
    for (int reg = 0; reg < 4; reg++) {
      int op = ob + reg;
      float ba = bias[op], bg = bias[H + op];
      float* orow = &out[(bb * H + op) * Lseq + l0 + wl * 64 + n];
#pragma unroll
      for (int lt = 0; lt < 4; lt++) {
        float a = acc_a[mt][lt][reg] + ba;
        float g = acc_g[mt][lt][reg] + bg;
        orow[lt * 16] = a / (1.0f + expf(-g));
      }
    }
  }
}

extern "C" void kernel_launch(void* const* d_in, const int* in_sizes, int n_in,
                              void* d_out, int out_size, void* d_ws, size_t ws_size,
                              hipStream_t stream) {
  const float* u      = (const float*)d_in[0];
  const float* log_dt = (const float*)d_in[1];
  const float* C      = (const float*)d_in[2];
  const float* lar    = (const float*)d_in[3];
  const float* aim    = (const float*)d_in[4];
  const float* Dp     = (const float*)d_in[5];
  const float* W      = (const float*)d_in[6];
  const float* bias   = (const float*)d_in[7];
  float* out = (float*)d_out;
  float* ws  = (float*)d_ws;
  float* P  = ws + P_OFF;
  float* S  = ws + S_OFF;
  float* yv = ws + Y_OFF;

  hipLaunchKernelGGL(k_params, dim3(HN / 256), dim3(256), 0, stream, log_dt, C, lar, aim, P);
  hipLaunchKernelGGL(k_scan1,  dim3(BH * NCH * N2 / 256), dim3(256), 0, stream, u, P, S);
  hipLaunchKernelGGL(k_prefix, dim3(BH * N2 / 256), dim3(256), 0, stream, P, S);
  hipLaunchKernelGGL(k_scan2,  dim3(BH * NCH / 64), dim3(256), 0, stream, u, P, S, Dp, yv);
  hipLaunchKernelGGL(k_gemm,   dim3(Lseq / 128, H / 64, Bsz), dim3(256), 0, stream, yv, W, bias, out);
}

// Round 4
// 191.310 us; speedup vs baseline: 1.9248x; 1.1106x over previous
//
#include <hip/hip_runtime.h>
#include <math.h>

#define H 256
#define N2 32
#define Bsz 8
#define Lseq 4096
#define BH (Bsz*H)          // 2048 sequences
#define NCH 32              // chunks along L
#define LC (Lseq/NCH)       // 128 chunk length
#define HN (H*N2)           // 8192

// workspace layout (float slots):
//  P  : 6*HN                [wr, wi, wLr, wLi, 2*Ctr, 2*Cti]  fp32
//  S  : BH*NCH*N2*2         chunk states fp32 (scan1 writes local finals; prefix -> incoming)
//  yb : BH*Lseq bf16        post-GELU activations (ushort)
//  Wb : 512*256 bf16        pre-converted W
//  kb : H*128 bf16          conv kernel k[h][d]
//  Eb : H*128*64 bf16       emission basis E[h][j][p]
#define P_OFF  0
#define S_OFF  (6*HN)
#define Y_OFF  (S_OFF + BH*NCH*N2*2)
#define WB_OFF (Y_OFF + (BH*Lseq/2))
#define KB_OFF (WB_OFF + (512*256/2))
#define EB_OFF (KB_OFF + (H*128/2))

typedef __attribute__((ext_vector_type(8))) short bf16x8;
typedef __attribute__((ext_vector_type(8))) unsigned short u16x8;
typedef __attribute__((ext_vector_type(4))) float f32x4;

__device__ __forceinline__ unsigned short f2bf(float x) {
  union { float f; unsigned int u; } v; v.f = x;
  unsigned int r = v.u + 0x7fffu + ((v.u >> 16) & 1u);  // round-to-nearest-even
  return (unsigned short)(r >> 16);
}
__device__ __forceinline__ unsigned int packbf(float lo, float hi) {
  return (unsigned int)f2bf(lo) | ((unsigned int)f2bf(hi) << 16);
}

// ---------------- K0: per-(h,n) parameters ----------------
__global__ void k_params(const float* __restrict__ log_dt, const float* __restrict__ C,
                         const float* __restrict__ lar, const float* __restrict__ aim,
                         float* __restrict__ P) {
  int i = blockIdx.x * blockDim.x + threadIdx.x;
  if (i >= HN) return;
  int h = i >> 5;
  float dt  = expf(log_dt[h]);
  float Ar  = -expf(lar[i]);
  float Ai  = aim[i];
  float dAr = Ar * dt, dAi = Ai * dt;
  float er  = expf(dAr);
  float wr  = er * cosf(dAi);
  float wi  = er * sinf(dAi);
  float eLr = expf(dAr * (float)LC);
  float wLr = eLr * cosf(dAi * (float)LC);
  float wLi = eLr * sinf(dAi * (float)LC);
  float emr = wr - 1.0f, emi = wi;
  float inv = 1.0f / (Ar * Ar + Ai * Ai);
  float qr  = (emr * Ar + emi * Ai) * inv;
  float qi  = (emi * Ar - emr * Ai) * inv;
  float Cr  = C[2 * i], Ci = C[2 * i + 1];
  float ctr = Cr * qr - Ci * qi;
  float cti = Cr * qi + Ci * qr;
  P[i]          = wr;
  P[HN + i]     = wi;
  P[2 * HN + i] = wLr;
  P[3 * HN + i] = wLi;
  P[4 * HN + i] = 2.0f * ctr;
  P[5 * HN + i] = 2.0f * cti;
}

// ---------------- K0b: W fp32 -> bf16 ----------------
__global__ void k_wconv(const float* __restrict__ W, unsigned short* __restrict__ Wb) {
  int i = blockIdx.x * 256 + threadIdx.x;     // i < 32768 float4s
  float4 v = *(const float4*)&W[i * 4];
  uint2 p; p.x = packbf(v.x, v.y); p.y = packbf(v.z, v.w);
  *(uint2*)&Wb[i * 4] = p;
}

// ---------------- K0c: basis: kb[h][j], Eb[h][j][p] (bf16) ----------------
// k[j]    = sum_n 2Re(Ct_n w_n^j)
// E[j][2n]   =  2Re(Ct_n w_n^{j+1})   (coeff of Fr)
// E[j][2n+1] = -2Im(Ct_n w_n^{j+1})   (coeff of Fi)
__global__ void k_basis(const float* __restrict__ log_dt, const float* __restrict__ lar,
                        const float* __restrict__ aim, const float* __restrict__ P,
                        unsigned short* __restrict__ kb, unsigned short* __restrict__ Eb) {
  int h = blockIdx.x;
  int j = threadIdx.x;                        // 0..127
  float dt = expf(log_dt[h]);
  float kacc = 0.f;
  unsigned short* Erow = Eb + (h * 128 + j) * 64;
  for (int n = 0; n < 32; n++) {
    int hn = (h << 5) + n;
    float dAr = -expf(lar[hn]) * dt;
    float dAi = aim[hn] * dt;
    float c2r = P[4 * HN + hn], c2i = P[5 * HN + hn];
    // w^j for k
    float ej = expf(dAr * (float)j);
    float sj, cj; sincosf(dAi * (float)j, &sj, &cj);
    kacc = fmaf(c2r, ej * cj, fmaf(-c2i, ej * sj, kacc));
    // w^{j+1} for E
    float e1 = expf(dAr * (float)(j + 1));
    float s1, c1; sincosf(dAi * (float)(j + 1), &s1, &c1);
    float w1r = e1 * c1, w1i = e1 * s1;
    Erow[2 * n]     = f2bf(c2r * w1r - c2i * w1i);
    Erow[2 * n + 1] = f2bf(-(c2r * w1i + c2i * w1r));
  }
  kb[h * 128 + j] = f2bf(kacc);
}

// ---------------- K1: chunk-local scans -> S_c (fp32 exact) ----------------
__global__ __launch_bounds__(256) void k_scan1(const float* __restrict__ u,
                                               const float* __restrict__ P,
                                               float* __restrict__ S) {
  int t  = blockIdx.x * 256 + threadIdx.x;  // t < BH*NCH*N2
  int n  = t & 31;
  int c  = (t >> 5) & (NCH - 1);
  int bh = t >> 10;
  int h  = bh & (H - 1);
  int hn = (h << 5) + n;
  float wr = P[hn], wi = P[HN + hn];
  const float* up = u + bh * Lseq + c * LC;
  float xr = 0.f, xi = 0.f;
  for (int j = 0; j < LC; j += 4) {
    float4 uv = *(const float4*)(up + j);
#pragma unroll
    for (int jj = 0; jj < 4; jj++) {
      float u1 = ((const float*)&uv)[jj];
      float nr = fmaf(wr, xr, fmaf(-wi, xi, u1));
      float ni = fmaf(wr, xi, wi * xr);
      xr = nr; xi = ni;
    }
  }
  int si = (((bh * NCH + c) << 5) + n) << 1;
  S[si] = xr; S[si + 1] = xi;
}

// ---------------- K2: serial prefix over chunks (in place) ----------------
__global__ void k_prefix(const float* __restrict__ P, float* __restrict__ S) {
  int t = blockIdx.x * blockDim.x + threadIdx.x;  // t < BH*N2
  if (t >= BH * N2) return;
  int n = t & 31, bh = t >> 5;
  int hn = ((bh & (H - 1)) << 5) + n;
  float wLr = P[2 * HN + hn], wLi = P[3 * HN + hn];
  float fr = 0.f, fi = 0.f;
  for (int c = 0; c < NCH; c++) {
    int si = (((bh * NCH + c) << 5) + n) << 1;
    float sr = S[si], s1 = S[si + 1];
    S[si] = fr; S[si + 1] = fi;             // incoming state for chunk c
    float nr = fmaf(wLr, fr, fmaf(-wLi, fi, sr));
    float ni = fmaf(wLr, fi, fmaf(wLi, fr, s1));
    fr = nr; fi = ni;
  }
}

// ---------------- K3: MFMA emit: Y = U @ Tt + F @ E ; +D*u, GELU -> yb (bf16) ----------------
// Grid (H, 4). Block: 64 rows (b = mq*2 + r>>5, c = r&31) x 128 j, 4 waves (16 rows each).
// Tt[m][j] = k[j-m] built in LDS from kb; all frag reads are aligned ds_read_b128.
__global__ __launch_bounds__(256) void k_emit(const float* __restrict__ u,
                                              const float* __restrict__ S,
                                              const unsigned short* __restrict__ kb,
                                              const unsigned short* __restrict__ Eb,
                                              const float* __restrict__ Dp,
                                              unsigned short* __restrict__ yb) {
  __shared__ unsigned short Ul[64][72];    // A-operand: u rows (k-contig), then F rows
  __shared__ unsigned short Bl[128][72];   // B-operand: [n=j][k], Toeplitz then E
  __shared__ unsigned short kbuf[128];
  int h   = blockIdx.x;
  int mq  = blockIdx.y;
  int tid = threadIdx.x;
  int wv = tid >> 6, lane = tid & 63;
  int n16 = lane & 15, quad = lane >> 4;
  int m0 = wv * 16;
  f32x4 acc[8] = {};                        // nt = j-tile 0..7

  if (tid < 128) kbuf[tid] = kb[h * 128 + tid];

  // ---- Phase A: causal Toeplitz conv, K-slices ks = 0, 64 ----
  for (int ks = 0; ks < 128; ks += 64) {
    __syncthreads();                        // kbuf ready / prev mfma done
#pragma unroll
    for (int i = 0; i < 4; i++) {
      int e = tid + i * 256;                // 0..1023 float4s: 64 rows x 16
      int r = e >> 4, c4 = e & 15;
      int b = mq * 2 + (r >> 5), c = r & 31;
      const float* up = u + ((b * 256 + h) * 4096 + c * 128 + ks + c4 * 4);
      float4 v = *(const float4*)up;
      *(unsigned int*)&Ul[r][c4 * 4]     = packbf(v.x, v.y);
      *(unsigned int*)&Ul[r][c4 * 4 + 2] = packbf(v.z, v.w);
    }
#pragma unroll
    for (int i = 0; i < 32; i++) {
      int e = tid + i * 256;                // 0..8191: jj (0..127) x m (0..63)
      int jj = e >> 6, m = e & 63;
      int d = jj - ks - m;
      Bl[jj][m] = (d >= 0) ? kbuf[d] : (unsigned short)0;
    }
    __syncthreads();
#pragma unroll
    for (int ks2 = 0; ks2 < 64; ks2 += 32) {
      int kc = ks2 + quad * 8;
      bf16x8 af = *(const bf16x8*)&Ul[m0 + n16][kc];
#pragma unroll
      for (int nt = 0; nt < 8; nt++) {
        bf16x8 bf = *(const bf16x8*)&Bl[nt * 16 + n16][kc];
        acc[nt] = __builtin_amdgcn_mfma_f32_16x16x32_bf16(af, bf, acc[nt], 0, 0, 0);
      }
    }
  }

  // ---- Phase B: incoming-state emission, K = 64 ----
  __syncthreads();
#pragma unroll
  for (int i = 0; i < 4; i++) {
    int e = tid + i * 256;                  // 64 rows x 16 float4s of S
    int r = e >> 4, c4 = e & 15;
    int b = mq * 2 + (r >> 5), c = r & 31;
    const float* sp = S + ((b * 256 + h) * 32 + c) * 64 + c4 * 4;
    float4 v = *(const float4*)sp;
    *(unsigned int*)&Ul[r][c4 * 4]     = packbf(v.x, v.y);
    *(unsigned int*)&Ul[r][c4 * 4 + 2] = packbf(v.z, v.w);
  }
#pragma unroll
  for (int i = 0; i < 4; i++) {
    int e = tid + i * 256;                  // 1024 ushort8s: 128 jj x 8
    int jj = e >> 3, p8 = e & 7;
    *(u16x8*)&Bl[jj][p8 * 8] = *(const u16x8*)&Eb[(h * 128 + jj) * 64 + p8 * 8];
  }
  __syncthreads();
#pragma unroll
  for (int ks2 = 0; ks2 < 64; ks2 += 32) {
    int kc = ks2 + quad * 8;
    bf16x8 af = *(const bf16x8*)&Ul[m0 + n16][kc];
#pragma unroll
    for (int nt = 0; nt < 8; nt++) {
      bf16x8 bf = *(const bf16x8*)&Bl[nt * 16 + n16][kc];
      acc[nt] = __builtin_amdgcn_mfma_f32_16x16x32_bf16(af, bf, acc[nt], 0, 0, 0);
    }
  }

  // ---- epilogue: + D*u (fp32 reload, exact), exact GELU, bf16 store ----
  float Dh = Dp[h];
#pragma unroll
  for (int reg = 0; reg < 4; reg++) {
    int m = m0 + quad * 4 + reg;
    int b = mq * 2 + (m >> 5), c = m & 31;
    int base = (b * 256 + h) * 4096 + c * 128;
#pragma unroll
    for (int nt = 0; nt < 8; nt++) {
      int j = nt * 16 + n16;
      float uv = u[base + j];
      float v  = fmaf(Dh, uv, acc[nt][reg]);
      float ge = 0.5f * v * (1.0f + erff(v * 0.70710678118654752f));
      yb[base + j] = f2bf(ge);
    }
  }
}

// ---------------- K4: MFMA bf16 GEMM: z = W@y + b ; out = a * sigmoid(g) ----------------
__global__ __launch_bounds__(256) void k_gemm(const unsigned short* __restrict__ yb,
                                              const unsigned short* __restrict__ Wb,
                                              const float* __restrict__ bias,
                                              float* __restrict__ out) {
  __shared__ unsigned short Ws[128][72];
  __shared__ unsigned short Ys[128][72];
  int tid  = threadIdx.x;
  int l0   = blockIdx.x * 128;
  int o0   = blockIdx.y * 64;
  int bb   = blockIdx.z;
  int wave = tid >> 6;
  int lane = tid & 63;
  int wo   = wave & 1;
  int wl   = wave >> 1;
  int n    = lane & 15;
  int quad = lane >> 4;

  f32x4 acc_a[2][4] = {};
  f32x4 acc_g[2][4] = {};

  for (int kk = 0; kk < H; kk += 64) {
    // ---- stage W tile: plain ushort8 copies ----
#pragma unroll
    for (int i = 0; i < 4; i++) {
      int e = tid + i * 256;               // 0..1023 ushort8s: 128 rows x 8
      int r = e >> 3, s = e & 7;
      int gr = (r < 64) ? (o0 + r) : (192 + o0 + r);
      *(u16x8*)&Ws[r][s * 8] = *(const u16x8*)&Wb[gr * 256 + kk + s * 8];
    }
    // ---- stage y tile transposed: thread owns k-col, ushort8 row reads, scalar LDS writes ----
    {
      int kcol = tid & 63;
      int lg0  = tid >> 6;
      const unsigned short* yrow = yb + (bb * 256 + kk + kcol) * 4096 + l0;
#pragma unroll
      for (int i = 0; i < 4; i++) {
        int l8 = (lg0 * 4 + i) * 8;        // 0,8,...,120
        u16x8 v = *(const u16x8*)&yrow[l8];
#pragma unroll
        for (int jj = 0; jj < 8; jj++)
          Ys[l8 + jj][kcol] = v[jj];
      }
    }
    __syncthreads();
#pragma unroll
    for (int ks = 0; ks < 64; ks += 32) {
      int kc = ks + quad * 8;
      bf16x8 af_a[2], af_g[2], bfr[4];
#pragma unroll
      for (int mt = 0; mt < 2; mt++) {
        af_a[mt] = *(const bf16x8*)&Ws[wo * 32 + mt * 16 + n][kc];
        af_g[mt] = *(const bf16x8*)&Ws[64 + wo * 32 + mt * 16 + n][kc];
      }
#pragma unroll
      for (int lt = 0; lt < 4; lt++)
        bfr[lt] = *(const bf16x8*)&Ys[wl * 64 + lt * 16 + n][kc];
#pragma unroll
      for (int mt = 0; mt < 2; mt++)
#pragma unroll
        for (int lt = 0; lt < 4; lt++) {
          acc_a[mt][lt] = __builtin_amdgcn_mfma_f32_16x16x32_bf16(af_a[mt], bfr[lt], acc_a[mt][lt], 0, 0, 0);
          acc_g[mt][lt] = __builtin_amdgcn_mfma_f32_16x16x32_bf16(af_g[mt], bfr[lt], acc_g[mt][lt], 0, 0, 0);
        }
    }
    __syncthreads();
  }
#pragma unroll
  for (int mt = 0; mt < 2; mt++) {
    int ob = o0 + wo * 32 + mt * 16 + quad * 4;
#pragma unroll
    for (int reg = 0; reg < 4; reg++) {
      int op = ob + reg;
      float ba = bias[op], bg = bias[H + op];
      float* orow = &out[(bb * H + op) * Lseq + l0 + wl * 64 + n];
#pragma unroll
      for (int lt = 0; lt < 4; lt++) {
        float a = acc_a[mt][lt][reg] + ba;
        float g = acc_g[mt][lt][reg] + bg;
        orow[lt * 16] = a / (1.0f + expf(-g));
      }
    }
  }
}

extern "C" void kernel_launch(void* const* d_in, const int* in_sizes, int n_in,
                              void* d_out, int out_size, void* d_ws, size_t ws_size,
                              hipStream_t stream) {
  const float* u      = (const float*)d_in[0];
  const float* log_dt = (const float*)d_in[1];
  const float* C      = (const float*)d_in[2];
  const float* lar    = (const float*)d_in[3];
  const float* aim    = (const float*)d_in[4];
  const float* Dp     = (const float*)d_in[5];
  const float* W      = (const float*)d_in[6];
  const float* bias   = (const float*)d_in[7];
  float* out = (float*)d_out;
  float* ws  = (float*)d_ws;
  float* P   = ws + P_OFF;
  float* S   = ws + S_OFF;
  unsigned short* yb  = (unsigned short*)(ws + Y_OFF);
  unsigned short* Wb  = (unsigned short*)(ws + WB_OFF);
  unsigned short* kbg = (unsigned short*)(ws + KB_OFF);
  unsigned short* Ebg = (unsigned short*)(ws + EB_OFF);

  hipLaunchKernelGGL(k_params, dim3(HN / 256), dim3(256), 0, stream, log_dt, C, lar, aim, P);
  hipLaunchKernelGGL(k_wconv,  dim3(128), dim3(256), 0, stream, W, Wb);
  hipLaunchKernelGGL(k_basis,  dim3(H), dim3(128), 0, stream, log_dt, lar, aim, P, kbg, Ebg);
  hipLaunchKernelGGL(k_scan1,  dim3(BH * NCH * N2 / 256), dim3(256), 0, stream, u, P, S);
  hipLaunchKernelGGL(k_prefix, dim3(BH * N2 / 256), dim3(256), 0, stream, P, S);
  hipLaunchKernelGGL(k_emit,   dim3(H, 4), dim3(256), 0, stream, u, S, kbg, Ebg, Dp, yb);
  hipLaunchKernelGGL(k_gemm,   dim3(Lseq / 128, H / 64, Bsz), dim3(256), 0, stream, yb, Wb, bias, out);
}

// Round 5
// 174.780 us; speedup vs baseline: 2.1068x; 1.0946x over previous
//
#include <hip/hip_runtime.h>
#include <math.h>

#define H 256
#define N2 32
#define Bsz 8
#define Lseq 4096
#define BH (Bsz*H)          // 2048 sequences
#define NCH 32              // chunks along L
#define LC (Lseq/NCH)       // 128 chunk length
#define HN (H*N2)           // 8192

// workspace layout (float slots):
//  S  : BH*NCH*N2*2 fp32    chunk states (k_state: local finals; k_prefix -> incoming)
//  yb : BH*Lseq bf16        post-GELU activations
//  Wb : 512*256 bf16        pre-converted W
//  kb : H*128 bf16          conv kernel k[h][d]
//  Eb : H*128*64 bf16       emission basis E[h][j][p]   (j-major, p-contig)
//  Vb : H*64*128 bf16       state basis  V[h][p][j]     (p-major, j-contig)
#define S_OFF  0
#define Y_OFF  (S_OFF + BH*NCH*N2*2)
#define WB_OFF (Y_OFF + (BH*Lseq/2))
#define KB_OFF (WB_OFF + (512*256/2))
#define EB_OFF (KB_OFF + (H*128/2))
#define VB_OFF (EB_OFF + (H*128*64/2))

typedef __attribute__((ext_vector_type(8))) short bf16x8;
typedef __attribute__((ext_vector_type(8))) unsigned short u16x8;
typedef __attribute__((ext_vector_type(4))) float f32x4;

__device__ __forceinline__ unsigned short f2bf(float x) {
  union { float f; unsigned int u; } v; v.f = x;
  unsigned int r = v.u + 0x7fffu + ((v.u >> 16) & 1u);  // round-to-nearest-even
  return (unsigned short)(r >> 16);
}
__device__ __forceinline__ unsigned int packbf(float lo, float hi) {
  return (unsigned int)f2bf(lo) | ((unsigned int)f2bf(hi) << 16);
}

// ---------------- K0: prep — W->bf16, conv kernel kb, bases Eb & Vb ----------------
// grid 256 (h), block 128 (j). Computes Ct etc. directly from raw inputs.
__global__ __launch_bounds__(128) void k_prep(const float* __restrict__ log_dt,
                                              const float* __restrict__ C,
                                              const float* __restrict__ lar,
                                              const float* __restrict__ aim,
                                              const float* __restrict__ W,
                                              unsigned short* __restrict__ Wb,
                                              unsigned short* __restrict__ kb,
                                              unsigned short* __restrict__ Eb,
                                              unsigned short* __restrict__ Vb) {
  int h = blockIdx.x;
  int j = threadIdx.x;                        // 0..127
  // ---- W fp32 -> bf16: one float4 per thread (256*128 = 32768 = all of W/4) ----
  {
    int i = h * 128 + j;
    float4 v = *(const float4*)&W[i * 4];
    uint2 p; p.x = packbf(v.x, v.y); p.y = packbf(v.z, v.w);
    *(uint2*)&Wb[i * 4] = p;
  }
  float dt = expf(log_dt[h]);
  float kacc = 0.f;
  unsigned short* Erow = Eb + (h * 128 + j) * 64;
  for (int n = 0; n < 32; n++) {
    int hn = (h << 5) + n;
    float Ar = -expf(lar[hn]), Ai = aim[hn];
    float dAr = Ar * dt, dAi = Ai * dt;
    float er = expf(dAr), sw, cw;
    sincosf(dAi, &sw, &cw);
    float wr = er * cw, wi = er * sw;
    float emr = wr - 1.f, emi = wi;
    float inv = 1.f / (Ar * Ar + Ai * Ai);
    float qr = (emr * Ar + emi * Ai) * inv;
    float qi = (emi * Ar - emr * Ai) * inv;
    float Cr = C[2 * hn], Ci = C[2 * hn + 1];
    float c2r = 2.f * (Cr * qr - Ci * qi);    // 2*Ct
    float c2i = 2.f * (Cr * qi + Ci * qr);
    // k[j] += Re(2Ct * w^j)
    float ej = expf(dAr * (float)j), sj, cj;
    sincosf(dAi * (float)j, &sj, &cj);
    kacc = fmaf(c2r, ej * cj, fmaf(-c2i, ej * sj, kacc));
    // E[j][2n] = Re(2Ct w^{j+1}), E[j][2n+1] = -Im(2Ct w^{j+1})
    float e1 = expf(dAr * (float)(j + 1)), s1, c1;
    sincosf(dAi * (float)(j + 1), &s1, &c1);
    float w1r = e1 * c1, w1i = e1 * s1;
    Erow[2 * n]     = f2bf(c2r * w1r - c2i * w1i);
    Erow[2 * n + 1] = f2bf(-(c2r * w1i + c2i * w1r));
    // V[2n][j] = Re(w^{127-j}), V[2n+1][j] = Im(w^{127-j})
    float ev = expf(dAr * (float)(127 - j)), sv, cv;
    sincosf(dAi * (float)(127 - j), &sv, &cv);
    Vb[(h * 64 + 2 * n) * 128 + j]     = f2bf(ev * cv);
    Vb[(h * 64 + 2 * n + 1) * 128 + j] = f2bf(ev * sv);
  }
  kb[h * 128 + j] = f2bf(kacc);
}

// ---------------- K1: MFMA chunk states: S[b,h,c,n] = sum_j u[...j] w^{127-j} ----------------
// Grid (H,4). Block: 64 rows (b,c) x 128 K(j) A-tile vs 64 p B-tile; 4 waves x 16 rows.
__global__ __launch_bounds__(256) void k_state(const float* __restrict__ u,
                                               const unsigned short* __restrict__ Vb,
                                               float* __restrict__ S) {
  __shared__ unsigned short Ul[64][136];   // stride 272 B = 17*16: aligned b128 reads
  __shared__ unsigned short Bl[64][136];
  int h   = blockIdx.x;
  int mq  = blockIdx.y;
  int tid = threadIdx.x;
  int wv = tid >> 6, lane = tid & 63;
  int n16 = lane & 15, quad = lane >> 4;
  int m0 = wv * 16;
  f32x4 acc[4] = {};
  // stage A: 64 rows x 128 fp32 -> bf16 (2048 float4s)
#pragma unroll
  for (int i = 0; i < 8; i++) {
    int e = tid + i * 256;
    int r = e >> 5, c4 = e & 31;
    int b = mq * 2 + (r >> 5), c = r & 31;
    float4 v = *(const float4*)&u[((b * 256 + h) * 4096 + c * 128 + c4 * 4)];
    *(unsigned int*)&Ul[r][c4 * 4]     = packbf(v.x, v.y);
    *(unsigned int*)&Ul[r][c4 * 4 + 2] = packbf(v.z, v.w);
  }
  // stage B: Vb[h]: 64 p-rows x 128 (1024 ushort8s)
#pragma unroll
  for (int i = 0; i < 4; i++) {
    int e = tid + i * 256;
    int p = e >> 4, s8 = e & 15;
    *(u16x8*)&Bl[p][s8 * 8] = *(const u16x8*)&Vb[(h * 64 + p) * 128 + s8 * 8];
  }
  __syncthreads();
#pragma unroll
  for (int ks = 0; ks < 128; ks += 32) {
    int kc = ks + quad * 8;
    bf16x8 af = *(const bf16x8*)&Ul[m0 + n16][kc];
#pragma unroll
    for (int nt = 0; nt < 4; nt++) {
      bf16x8 bf = *(const bf16x8*)&Bl[nt * 16 + n16][kc];
      acc[nt] = __builtin_amdgcn_mfma_f32_16x16x32_bf16(af, bf, acc[nt], 0, 0, 0);
    }
  }
#pragma unroll
  for (int reg = 0; reg < 4; reg++) {
    int m = m0 + quad * 4 + reg;
    int b = mq * 2 + (m >> 5), c = m & 31;
#pragma unroll
    for (int nt = 0; nt < 4; nt++) {
      int p = nt * 16 + n16;
      S[((b * 256 + h) * 32 + c) * 64 + p] = acc[nt][reg];
    }
  }
}

// ---------------- K2: serial prefix over chunks (in place), wL computed inline ----------------
__global__ void k_prefix(const float* __restrict__ log_dt, const float* __restrict__ lar,
                         const float* __restrict__ aim, float* __restrict__ S) {
  int t = blockIdx.x * blockDim.x + threadIdx.x;  // t < BH*N2
  if (t >= BH * N2) return;
  int n = t & 31, bh = t >> 5;
  int h = bh & (H - 1);
  int hn = (h << 5) + n;
  float dt  = expf(log_dt[h]);
  float dAr = -expf(lar[hn]) * dt, dAi = aim[hn] * dt;
  float eL = expf(dAr * (float)LC), sL, cL;
  sincosf(dAi * (float)LC, &sL, &cL);
  float wLr = eL * cL, wLi = eL * sL;
  float fr = 0.f, fi = 0.f;
  for (int c = 0; c < NCH; c++) {
    int si = (((bh * NCH + c) << 5) + n) << 1;
    float sr = S[si], s1 = S[si + 1];
    S[si] = fr; S[si + 1] = fi;             // incoming state for chunk c
    float nr = fmaf(wLr, fr, fmaf(-wLi, fi, sr));
    float ni = fmaf(wLr, fi, fmaf(wLi, fr, s1));
    fr = nr; fi = ni;
  }
}

// ---------------- K3: MFMA emit: Y = U @ Tt + F @ E ; +D*u, GELU -> yb (bf16) ----------------
__global__ __launch_bounds__(256) void k_emit(const float* __restrict__ u,
                                              const float* __restrict__ S,
                                              const unsigned short* __restrict__ kb,
                                              const unsigned short* __restrict__ Eb,
                                              const float* __restrict__ Dp,
                                              unsigned short* __restrict__ yb) {
  __shared__ unsigned short Ul[64][72];    // A-operand: u rows (k-contig), then F rows
  __shared__ unsigned short Bl[128][72];   // B-operand: [n=j][k], Toeplitz then E
  __shared__ unsigned short kbuf[128];
  int h   = blockIdx.x;
  int mq  = blockIdx.y;
  int tid = threadIdx.x;
  int wv = tid >> 6, lane = tid & 63;
  int n16 = lane & 15, quad = lane >> 4;
  int m0 = wv * 16;
  f32x4 acc[8] = {};                        // nt = j-tile 0..7

  if (tid < 128) kbuf[tid] = kb[h * 128 + tid];

  // ---- Phase A: causal Toeplitz conv, K-slices ks = 0, 64 ----
  for (int ks = 0; ks < 128; ks += 64) {
    __syncthreads();
#pragma unroll
    for (int i = 0; i < 4; i++) {
      int e = tid + i * 256;
      int r = e >> 4, c4 = e & 15;
      int b = mq * 2 + (r >> 5), c = r & 31;
      const float* up = u + ((b * 256 + h) * 4096 + c * 128 + ks + c4 * 4);
      float4 v = *(const float4*)up;
      *(unsigned int*)&Ul[r][c4 * 4]     = packbf(v.x, v.y);
      *(unsigned int*)&Ul[r][c4 * 4 + 2] = packbf(v.z, v.w);
    }
#pragma unroll
    for (int i = 0; i < 32; i++) {
      int e = tid + i * 256;
      int jj = e >> 6, m = e & 63;
      int d = jj - ks - m;
      Bl[jj][m] = (d >= 0) ? kbuf[d] : (unsigned short)0;
    }
    __syncthreads();
#pragma unroll
    for (int ks2 = 0; ks2 < 64; ks2 += 32) {
      int kc = ks2 + quad * 8;
      bf16x8 af = *(const bf16x8*)&Ul[m0 + n16][kc];
#pragma unroll
      for (int nt = 0; nt < 8; nt++) {
        bf16x8 bf = *(const bf16x8*)&Bl[nt * 16 + n16][kc];
        acc[nt] = __builtin_amdgcn_mfma_f32_16x16x32_bf16(af, bf, acc[nt], 0, 0, 0);
      }
    }
  }

  // ---- Phase B: incoming-state emission, K = 64 ----
  __syncthreads();
#pragma unroll
  for (int i = 0; i < 4; i++) {
    int e = tid + i * 256;
    int r = e >> 4, c4 = e & 15;
    int b = mq * 2 + (r >> 5), c = r & 31;
    const float* sp = S + ((b * 256 + h) * 32 + c) * 64 + c4 * 4;
    float4 v = *(const float4*)sp;
    *(unsigned int*)&Ul[r][c4 * 4]     = packbf(v.x, v.y);
    *(unsigned int*)&Ul[r][c4 * 4 + 2] = packbf(v.z, v.w);
  }
#pragma unroll
  for (int i = 0; i < 4; i++) {
    int e = tid + i * 256;
    int jj = e >> 3, p8 = e & 7;
    *(u16x8*)&Bl[jj][p8 * 8] = *(const u16x8*)&Eb[(h * 128 + jj) * 64 + p8 * 8];
  }
  __syncthreads();
#pragma unroll
  for (int ks2 = 0; ks2 < 64; ks2 += 32) {
    int kc = ks2 + quad * 8;
    bf16x8 af = *(const bf16x8*)&Ul[m0 + n16][kc];
#pragma unroll
    for (int nt = 0; nt < 8; nt++) {
      bf16x8 bf = *(const bf16x8*)&Bl[nt * 16 + n16][kc];
      acc[nt] = __builtin_amdgcn_mfma_f32_16x16x32_bf16(af, bf, acc[nt], 0, 0, 0);
    }
  }

  // ---- epilogue: + D*u (fp32 reload, exact), exact GELU, bf16 store ----
  float Dh = Dp[h];
#pragma unroll
  for (int reg = 0; reg < 4; reg++) {
    int m = m0 + quad * 4 + reg;
    int b = mq * 2 + (m >> 5), c = m & 31;
    int base = (b * 256 + h) * 4096 + c * 128;
#pragma unroll
    for (int nt = 0; nt < 8; nt++) {
      int j = nt * 16 + n16;
      float uv = u[base + j];
      float v  = fmaf(Dh, uv, acc[nt][reg]);
      float ge = 0.5f * v * (1.0f + erff(v * 0.70710678118654752f));
      yb[base + j] = f2bf(ge);
    }
  }
}

// ---------------- K4: MFMA bf16 GEMM: z = W@y + b ; out = a * sigmoid(g) ----------------
__global__ __launch_bounds__(256) void k_gemm(const unsigned short* __restrict__ yb,
                                              const unsigned short* __restrict__ Wb,
                                              const float* __restrict__ bias,
                                              float* __restrict__ out) {
  __shared__ unsigned short Ws[128][72];
  __shared__ unsigned short Ys[128][72];
  int tid  = threadIdx.x;
  int l0   = blockIdx.x * 128;
  int o0   = blockIdx.y * 64;
  int bb   = blockIdx.z;
  int wave = tid >> 6;
  int lane = tid & 63;
  int wo   = wave & 1;
  int wl   = wave >> 1;
  int n    = lane & 15;
  int quad = lane >> 4;

  f32x4 acc_a[2][4] = {};
  f32x4 acc_g[2][4] = {};

  for (int kk = 0; kk < H; kk += 64) {
#pragma unroll
    for (int i = 0; i < 4; i++) {
      int e = tid + i * 256;
      int r = e >> 3, s = e & 7;
      int gr = (r < 64) ? (o0 + r) : (192 + o0 + r);
      *(u16x8*)&Ws[r][s * 8] = *(const u16x8*)&Wb[gr * 256 + kk + s * 8];
    }
    {
      int kcol = tid & 63;
      int lg0  = tid >> 6;
      const unsigned short* yrow = yb + (bb * 256 + kk + kcol) * 4096 + l0;
#pragma unroll
      for (int i = 0; i < 4; i++) {
        int l8 = (lg0 * 4 + i) * 8;
        u16x8 v = *(const u16x8*)&yrow[l8];
#pragma unroll
        for (int jj = 0; jj < 8; jj++)
          Ys[l8 + jj][kcol] = v[jj];
      }
    }
    __syncthreads();
#pragma unroll
    for (int ks = 0; ks < 64; ks += 32) {
      int kc = ks + quad * 8;
      bf16x8 af_a[2], af_g[2], bfr[4];
#pragma unroll
      for (int mt = 0; mt < 2; mt++) {
        af_a[mt] = *(const bf16x8*)&Ws[wo * 32 + mt * 16 + n][kc];
        af_g[mt] = *(const bf16x8*)&Ws[64 + wo * 32 + mt * 16 + n][kc];
      }
#pragma unroll
      for (int lt = 0; lt < 4; lt++)
        bfr[lt] = *(const bf16x8*)&Ys[wl * 64 + lt * 16 + n][kc];
#pragma unroll
      for (int mt = 0; mt < 2; mt++)
#pragma unroll
        for (int lt = 0; lt < 4; lt++) {
          acc_a[mt][lt] = __builtin_amdgcn_mfma_f32_16x16x32_bf16(af_a[mt], bfr[lt], acc_a[mt][lt], 0, 0, 0);
          acc_g[mt][lt] = __builtin_amdgcn_mfma_f32_16x16x32_bf16(af_g[mt], bfr[lt], acc_g[mt][lt], 0, 0, 0);
        }
    }
    __syncthreads();
  }
#pragma unroll
  for (int mt = 0; mt < 2; mt++) {
    int ob = o0 + wo * 32 + mt * 16 + quad * 4;
#pragma unroll
    for (int reg = 0; reg < 4; reg++) {
      int op = ob + reg;
      float ba = bias[op], bg = bias[H + op];
      float* orow = &out[(bb * H + op) * Lseq + l0 + wl * 64 + n];
#pragma unroll
      for (int lt = 0; lt < 4; lt++) {
        float a = acc_a[mt][lt][reg] + ba;
        float g = acc_g[mt][lt][reg] + bg;
        orow[lt * 16] = a / (1.0f + expf(-g));
      }
    }
  }
}

extern "C" void kernel_launch(void* const* d_in, const int* in_sizes, int n_in,
                              void* d_out, int out_size, void* d_ws, size_t ws_size,
                              hipStream_t stream) {
  const float* u      = (const float*)d_in[0];
  const float* log_dt = (const float*)d_in[1];
  const float* C      = (const float*)d_in[2];
  const float* lar    = (const float*)d_in[3];
  const float* aim    = (const float*)d_in[4];
  const float* Dp     = (const float*)d_in[5];
  const float* W      = (const float*)d_in[6];
  const float* bias   = (const float*)d_in[7];
  float* out = (float*)d_out;
  float* ws  = (float*)d_ws;
  float* S   = ws + S_OFF;
  unsigned short* yb  = (unsigned short*)(ws + Y_OFF);
  unsigned short* Wb  = (unsigned short*)(ws + WB_OFF);
  unsigned short* kbg = (unsigned short*)(ws + KB_OFF);
  unsigned short* Ebg = (unsigned short*)(ws + EB_OFF);
  unsigned short* Vbg = (unsigned short*)(ws + VB_OFF);

  hipLaunchKernelGGL(k_prep,   dim3(H), dim3(128), 0, stream, log_dt, C, lar, aim, W, Wb, kbg, Ebg, Vbg);
  hipLaunchKernelGGL(k_state,  dim3(H, 4), dim3(256), 0, stream, u, Vbg, S);
  hipLaunchKernelGGL(k_prefix, dim3(BH * N2 / 256), dim3(256), 0, stream, log_dt, lar, aim, S);
  hipLaunchKernelGGL(k_emit,   dim3(H, 4), dim3(256), 0, stream, u, S, kbg, Ebg, Dp, yb);
  hipLaunchKernelGGL(k_gemm,   dim3(Lseq / 128, H / 64, Bsz), dim3(256), 0, stream, yb, Wb, bias, out);
}